// Round 9
// baseline (2363.448 us; speedup 1.0000x reference)
//
#include <hip/hip_runtime.h>

// Problem constants
#define LL   8
#define HH   4
#define QQ   64
#define DD   512
#define NN   2048
#define DFFC 2048
#define ENTRY_CAP (1 << 17)
#define CHUNK 8
#define APPLY_BLOCKS 2048
#define LCAP 2048   // per-block LDS entry staging capacity

typedef short     bf16x8 __attribute__((ext_vector_type(8)));  // 8 bf16 = 4 VGPR
typedef float     f32x4  __attribute__((ext_vector_type(4)));  // MFMA C/D frag
typedef unsigned short u16;

// fp32 -> (hi, lo) bf16 split, RNE. x ~= hi + lo with ~16-bit mantissa coverage.
__device__ inline void splitf(float v, u16& h, u16& l)
{
    unsigned u  = __float_as_uint(v);
    unsigned uh = u + (0x7FFFu + ((u >> 16) & 1u));
    h = (u16)(uh >> 16);
    float fh = __uint_as_float(((unsigned)h) << 16);
    float r  = v - fh;
    unsigned ur = __float_as_uint(r);
    unsigned ul = ur + (0x7FFFu + ((ur >> 16) & 1u));
    l = (u16)(ul >> 16);
}

// Monotone fp32 <-> uint mapping for atomicMax on floats (no NaNs in data).
__device__ inline unsigned mapf(float f)
{
    unsigned u = __float_as_uint(f);
    return (u >> 31) ? ~u : (u | 0x80000000u);
}
__device__ inline float unmapf(unsigned u)
{
    return (u >> 31) ? __uint_as_float(u ^ 0x80000000u) : __uint_as_float(~u);
}

// ---------------------------------------------------------------------------
// Split-bf16 MFMA GEMM (NT): C[M,N] = A[M,K] @ B[N,K]^T as hi*hi+hi*lo+lo*hi
// (fp32 accumulate). Block 256 thr = 4 waves (2x2). Col tile fixed 128 (4
// j-frags/wave); row tile = MI*32 (MI i-frags/wave). MI=4 -> 128x128 (R6-
// proven); MI=2/1 -> more blocks for occupancy on small grids.
// ---------------------------------------------------------------------------
template <int MI, int BIAS, int RELU, int WF32, int WSPLIT>
__global__ __launch_bounds__(256) void mgemm_k(
    const u16* __restrict__ Ahi, const u16* __restrict__ Alo,
    const u16* __restrict__ Bhi, const u16* __restrict__ Blo,
    float* __restrict__ C, u16* __restrict__ Chi, u16* __restrict__ Clo,
    const float* __restrict__ bias,
    int M, int N, int K, int lda, int ldb, int ldc,
    long sAoff, long sBoff, long sCoff)
{
    const int bz = blockIdx.z;
    Ahi += bz * sAoff;  Alo += bz * sAoff;
    Bhi += bz * sBoff;  Blo += bz * sBoff;
    const long cOff = (long)bz * sCoff;

    const int tid  = threadIdx.x;
    const int wave = tid >> 6, lane = tid & 63;
    const int quad = lane >> 4, l15 = lane & 15;
    const int wy = wave >> 1, wx = wave & 1;
    const int mBase = blockIdx.y * (MI * 32) + wy * (MI * 16);
    const int nBase = blockIdx.x * 128 + wx * 64;

    f32x4 acc[MI][4];
#pragma unroll
    for (int i = 0; i < MI; i++)
#pragma unroll
        for (int j = 0; j < 4; j++)
            acc[i][j] = (f32x4){0.f, 0.f, 0.f, 0.f};

    for (int k0 = 0; k0 < K; k0 += 32) {
        const int kk = k0 + quad * 8;
        bf16x8 ah[MI], al[MI], bh[4], bl[4];
#pragma unroll
        for (int i = 0; i < MI; i++) {
            long ar = (long)(mBase + i * 16 + l15) * lda + kk;
            ah[i] = *(const bf16x8*)(Ahi + ar);
            al[i] = *(const bf16x8*)(Alo + ar);
        }
#pragma unroll
        for (int j = 0; j < 4; j++) {
            long br = (long)(nBase + j * 16 + l15) * ldb + kk;
            bh[j] = *(const bf16x8*)(Bhi + br);
            bl[j] = *(const bf16x8*)(Blo + br);
        }
#pragma unroll
        for (int i = 0; i < MI; i++)
#pragma unroll
            for (int j = 0; j < 4; j++) {
                acc[i][j] = __builtin_amdgcn_mfma_f32_16x16x32_bf16(ah[i], bh[j], acc[i][j], 0, 0, 0);
                acc[i][j] = __builtin_amdgcn_mfma_f32_16x16x32_bf16(ah[i], bl[j], acc[i][j], 0, 0, 0);
                acc[i][j] = __builtin_amdgcn_mfma_f32_16x16x32_bf16(al[i], bh[j], acc[i][j], 0, 0, 0);
            }
    }

#pragma unroll
    for (int i = 0; i < MI; i++) {
#pragma unroll
        for (int j = 0; j < 4; j++) {
            const int n = nBase + j * 16 + l15;
            const float bv = BIAS ? bias[n] : 0.0f;
#pragma unroll
            for (int r = 0; r < 4; r++) {
                const int m = mBase + i * 16 + quad * 4 + r;
                float v = acc[i][j][r] + bv;
                if (RELU) v = fmaxf(v, 0.0f);
                const long o = cOff + (long)m * ldc + n;
                if (WF32) C[o] = v;
                if (WSPLIT) {
                    u16 h, l;
                    splitf(v, h, l);
                    Chi[o] = h;
                    Clo[o] = l;
                }
            }
        }
    }
}

// ---------------------------------------------------------------------------
// Fused mask path, pass A: per-head Gram tile S = G G^T in regs; row-max
// reduce -> global atomicMax. S never materialized. (R8-proven)
// ---------------------------------------------------------------------------
__global__ __launch_bounds__(256) void smax_k(
    const u16* __restrict__ Ghi, const u16* __restrict__ Glo,
    unsigned* __restrict__ rowmaxU)
{
    const int h = blockIdx.z;
    const u16* Ah = Ghi + h * QQ;
    const u16* Al = Glo + h * QQ;
    const int lda = HH * QQ;

    const int tid  = threadIdx.x;
    const int wave = tid >> 6, lane = tid & 63;
    const int quad = lane >> 4, l15 = lane & 15;
    const int wy = wave >> 1, wx = wave & 1;
    const int rB = blockIdx.y * 128 + wy * 64;
    const int cB = blockIdx.x * 128 + wx * 64;

    f32x4 acc[4][4];
#pragma unroll
    for (int i = 0; i < 4; i++)
#pragma unroll
        for (int j = 0; j < 4; j++)
            acc[i][j] = (f32x4){0.f, 0.f, 0.f, 0.f};

    for (int k0 = 0; k0 < QQ; k0 += 32) {
        const int kk = k0 + quad * 8;
        bf16x8 ah[4], al[4], bh[4], bl[4];
#pragma unroll
        for (int i = 0; i < 4; i++) {
            long ar = (long)(rB + i * 16 + l15) * lda + kk;
            ah[i] = *(const bf16x8*)(Ah + ar);
            al[i] = *(const bf16x8*)(Al + ar);
            long br = (long)(cB + i * 16 + l15) * lda + kk;
            bh[i] = *(const bf16x8*)(Ah + br);
            bl[i] = *(const bf16x8*)(Al + br);
        }
#pragma unroll
        for (int i = 0; i < 4; i++)
#pragma unroll
            for (int j = 0; j < 4; j++) {
                acc[i][j] = __builtin_amdgcn_mfma_f32_16x16x32_bf16(ah[i], bh[j], acc[i][j], 0, 0, 0);
                acc[i][j] = __builtin_amdgcn_mfma_f32_16x16x32_bf16(ah[i], bl[j], acc[i][j], 0, 0, 0);
                acc[i][j] = __builtin_amdgcn_mfma_f32_16x16x32_bf16(al[i], bh[j], acc[i][j], 0, 0, 0);
            }
    }

#pragma unroll
    for (int i = 0; i < 4; i++)
#pragma unroll
        for (int r = 0; r < 4; r++) {
            float mx = acc[i][0][r];
#pragma unroll
            for (int j = 1; j < 4; j++) mx = fmaxf(mx, acc[i][j][r]);
#pragma unroll
            for (int off = 1; off < 16; off <<= 1)
                mx = fmaxf(mx, __shfl_xor(mx, off, 64));
            if (l15 == 0)
                atomicMax(&rowmaxU[h * NN + rB + i * 16 + quad * 4 + r], mapf(mx));
        }
}

// ---------------------------------------------------------------------------
// Fused mask path, pass B: recompute IDENTICAL S tile, threshold, count, and
// emit entries. Entries are staged in an LDS list (LDS atomics) and flushed
// with ONE global atomicAdd per block -- removes the same-address counter
// serialization that made R8's sextract 65us. Overflow -> direct global.
// ---------------------------------------------------------------------------
__global__ __launch_bounds__(256) void sextract_k(
    const u16* __restrict__ Ghi, const u16* __restrict__ Glo,
    const unsigned* __restrict__ rowmaxU, int* __restrict__ rowcnt,
    unsigned int* __restrict__ entries, int* __restrict__ counter)
{
    const int h = blockIdx.z;
    const u16* Ah = Ghi + h * QQ;
    const u16* Al = Glo + h * QQ;
    const int lda = HH * QQ;

    const int tid  = threadIdx.x;
    const int wave = tid >> 6, lane = tid & 63;
    const int quad = lane >> 4, l15 = lane & 15;
    const int wy = wave >> 1, wx = wave & 1;
    const int rB = blockIdx.y * 128 + wy * 64;
    const int cB = blockIdx.x * 128 + wx * 64;

    __shared__ float thrS[128];
    __shared__ unsigned lbuf[LCAP];
    __shared__ int lcnt, gbase;
    if (tid == 0) lcnt = 0;
    if (tid < 128) {
        float mx = unmapf(rowmaxU[h * NN + blockIdx.y * 128 + tid]);
        thrS[tid] = (fabsf(mx) > 0.5f) ? mx - 0.5f : 3.402823466e38f;
    }
    __syncthreads();

    f32x4 acc[4][4];
#pragma unroll
    for (int i = 0; i < 4; i++)
#pragma unroll
        for (int j = 0; j < 4; j++)
            acc[i][j] = (f32x4){0.f, 0.f, 0.f, 0.f};

    for (int k0 = 0; k0 < QQ; k0 += 32) {
        const int kk = k0 + quad * 8;
        bf16x8 ah[4], al[4], bh[4], bl[4];
#pragma unroll
        for (int i = 0; i < 4; i++) {
            long ar = (long)(rB + i * 16 + l15) * lda + kk;
            ah[i] = *(const bf16x8*)(Ah + ar);
            al[i] = *(const bf16x8*)(Al + ar);
            long br = (long)(cB + i * 16 + l15) * lda + kk;
            bh[i] = *(const bf16x8*)(Ah + br);
            bl[i] = *(const bf16x8*)(Al + br);
        }
#pragma unroll
        for (int i = 0; i < 4; i++)
#pragma unroll
            for (int j = 0; j < 4; j++) {
                acc[i][j] = __builtin_amdgcn_mfma_f32_16x16x32_bf16(ah[i], bh[j], acc[i][j], 0, 0, 0);
                acc[i][j] = __builtin_amdgcn_mfma_f32_16x16x32_bf16(ah[i], bl[j], acc[i][j], 0, 0, 0);
                acc[i][j] = __builtin_amdgcn_mfma_f32_16x16x32_bf16(al[i], bh[j], acc[i][j], 0, 0, 0);
            }
    }

#pragma unroll
    for (int i = 0; i < 4; i++) {
#pragma unroll
        for (int r = 0; r < 4; r++) {
            const int lr  = wy * 64 + i * 16 + quad * 4 + r;
            const int row = h * NN + rB + i * 16 + quad * 4 + r;
            const float thr = thrS[lr];

            int c = 0;
#pragma unroll
            for (int j = 0; j < 4; j++) c += (acc[i][j][r] >= thr) ? 1 : 0;
            int cs = c;
#pragma unroll
            for (int off = 1; off < 16; off <<= 1) cs += __shfl_xor(cs, off, 64);
            if (l15 == 0 && cs > 0) atomicAdd(&rowcnt[row], cs);

#pragma unroll
            for (int j = 0; j < 4; j++) {
                if (acc[i][j][r] >= thr) {
                    unsigned ent = ((unsigned)row << 11) |
                                   (unsigned)(cB + j * 16 + l15);
                    int s = atomicAdd(&lcnt, 1);
                    if (s < LCAP) {
                        lbuf[s] = ent;
                    } else {
                        unsigned p = (unsigned)atomicAdd(counter, 1);
                        if (p < ENTRY_CAP) entries[p] = ent;
                    }
                }
            }
        }
    }

    __syncthreads();
    int n = lcnt;
    if (n > LCAP) n = LCAP;
    if (n > 0) {
        if (tid == 0) gbase = atomicAdd(counter, n);
        __syncthreads();
        for (int i2 = tid; i2 < n; i2 += 256) {
            unsigned p = (unsigned)(gbase + i2);
            if (p < ENTRY_CAP) entries[p] = lbuf[i2];
        }
    }
}

// ---------------------------------------------------------------------------
// initrow: zero rowmaxU[8192] and rowcnt[8192] (adjacent) per layer.
// ---------------------------------------------------------------------------
__global__ __launch_bounds__(256) void initrow_k(unsigned* __restrict__ p)
{
    p[blockIdx.x * 256 + threadIdx.x] = 0u;
}

// ---------------------------------------------------------------------------
// wrecip: wrecip[row] = active ? 1/max(cnt,1) : 0.
// ---------------------------------------------------------------------------
__global__ __launch_bounds__(256) void wrecip_k(
    const unsigned* __restrict__ rowmaxU, const int* __restrict__ rowcnt,
    float* __restrict__ wrecip)
{
    int i = blockIdx.x * 256 + threadIdx.x;
    float mx = unmapf(rowmaxU[i]);
    wrecip[i] = (fabsf(mx) > 0.5f) ? 1.0f / fmaxf((float)rowcnt[i], 1.0f) : 0.0f;
}

// ---------------------------------------------------------------------------
// split / splitw / zero / buildcsr / initattn / apply / ff2red / transpose
// (unchanged from R7/R8-passing code)
// ---------------------------------------------------------------------------
__global__ __launch_bounds__(256) void split_k(
    const float* __restrict__ src, u16* __restrict__ hi, u16* __restrict__ lo)
{
    int i = blockIdx.x * 256 + threadIdx.x;
    float4 v = ((const float4*)src)[i];
    ushort4 hv, lv;
    splitf(v.x, hv.x, lv.x);
    splitf(v.y, hv.y, lv.y);
    splitf(v.z, hv.z, lv.z);
    splitf(v.w, hv.w, lv.w);
    ((ushort4*)hi)[i] = hv;
    ((ushort4*)lo)[i] = lv;
}

__global__ __launch_bounds__(256) void splitw_k(
    const float* __restrict__ K_, const float* __restrict__ V_,
    const float* __restrict__ W1_, const float* __restrict__ W2_,
    u16* __restrict__ Khi, u16* __restrict__ Klo,
    u16* __restrict__ Vhi, u16* __restrict__ Vlo,
    u16* __restrict__ W1hi, u16* __restrict__ W1lo,
    u16* __restrict__ W2hi, u16* __restrict__ W2lo)
{
    int i = blockIdx.x * 256 + threadIdx.x;
    const float* s;
    u16 *h, *l;
    int off;
    if (i < 32768)       { s = K_;  h = Khi;  l = Klo;  off = i; }
    else if (i < 294912) { s = V_;  h = Vhi;  l = Vlo;  off = i - 32768; }
    else if (i < 557056) { s = W1_; h = W1hi; l = W1lo; off = i - 294912; }
    else                 { s = W2_; h = W2hi; l = W2lo; off = i - 557056; }
    float4 v = ((const float4*)s)[off];
    ushort4 hv, lv;
    splitf(v.x, hv.x, lv.x);
    splitf(v.y, hv.y, lv.y);
    splitf(v.z, hv.z, lv.z);
    splitf(v.w, hv.w, lv.w);
    ((ushort4*)h)[off] = hv;
    ((ushort4*)l)[off] = lv;
}

__global__ void zero_k(int* __restrict__ counters)
{
    if (threadIdx.x < LL) counters[threadIdx.x] = 0;
}

__global__ __launch_bounds__(256) void buildcsr_k(
    const unsigned int* __restrict__ entries, const int* __restrict__ counter,
    unsigned int* __restrict__ csr, int* __restrict__ colOff)
{
    __shared__ int hist[NN];
    __shared__ int part[256];
    const int t = threadIdx.x;
    int cnt = *counter;
    if (cnt > ENTRY_CAP) cnt = ENTRY_CAP;

    for (int i = t; i < NN; i += 256) hist[i] = 0;
    __syncthreads();
    for (int i = t; i < cnt; i += 256)
        atomicAdd(&hist[entries[i] & 2047], 1);
    __syncthreads();

    int e[8];
    int s = 0;
#pragma unroll
    for (int i = 0; i < 8; i++) { e[i] = s; s += hist[t * 8 + i]; }
    part[t] = s;
    __syncthreads();
    for (int off = 1; off < 256; off <<= 1) {
        int x = (t >= off) ? part[t - off] : 0;
        __syncthreads();
        part[t] += x;
        __syncthreads();
    }
    int base = (t > 0) ? part[t - 1] : 0;
    int my[8];
#pragma unroll
    for (int i = 0; i < 8; i++) my[i] = base + e[i];
#pragma unroll
    for (int i = 0; i < 8; i++) colOff[t * 8 + i] = my[i];
    if (t == 255) colOff[NN] = part[255];
    __syncthreads();
#pragma unroll
    for (int i = 0; i < 8; i++) hist[t * 8 + i] = my[i];
    __syncthreads();

    for (int i = t; i < cnt; i += 256) {
        unsigned v = entries[i];
        int slot = atomicAdd(&hist[v & 2047], 1);
        csr[slot] = v;
    }
}

__global__ __launch_bounds__(256) void initattn_k(
    const float* __restrict__ X, float* __restrict__ attnT)
{
    long i = (long)blockIdx.x * 256 + threadIdx.x;
    ((float4*)attnT)[i] = ((const float4*)X)[i];
}

__global__ __launch_bounds__(256) void apply_k(
    const unsigned int* __restrict__ csr, const int* __restrict__ colOff,
    const float* __restrict__ wrecip, const float* __restrict__ Yt,
    float* __restrict__ attnT)
{
    const int total = colOff[NN];
    const int tid = threadIdx.x;

    for (int base = blockIdx.x * CHUNK; base < total;
         base += gridDim.x * CHUNK) {
        int end = base + CHUNK;
        if (end > total) end = total;

        float a0 = 0.0f, a1 = 0.0f;
        int curM = -1;
        for (int e = base; e < end; e++) {
            unsigned v = csr[e];
            int m = v & 2047;
            int row = (int)(v >> 11);
            if (m != curM) {
                if (curM >= 0) {
                    atomicAdd(&attnT[(long)curM * DD + tid], a0);
                    atomicAdd(&attnT[(long)curM * DD + tid + 256], a1);
                }
                curM = m;
                a0 = a1 = 0.0f;
            }
            float w = wrecip[row];
            const float* y = Yt + (long)row * DD;
            a0 += w * y[tid];
            a1 += w * y[tid + 256];
        }
        if (curM >= 0) {
            atomicAdd(&attnT[(long)curM * DD + tid], a0);
            atomicAdd(&attnT[(long)curM * DD + tid + 256], a1);
        }
    }
}

__global__ __launch_bounds__(256) void ff2red_k(
    const float* __restrict__ Cpart, const float* __restrict__ b2,
    const float* __restrict__ attnT, float* __restrict__ Xn,
    u16* __restrict__ Xhi, u16* __restrict__ Xlo)
{
    int i = blockIdx.x * 256 + threadIdx.x;
    float4 v0 = ((const float4*)(Cpart))[i];
    float4 v1 = ((const float4*)(Cpart + 1048576))[i];
    float4 v2 = ((const float4*)(Cpart + 2097152))[i];
    float4 v3 = ((const float4*)(Cpart + 3145728))[i];
    float4 bv = ((const float4*)b2)[i & 127];
    float4 rv = ((const float4*)attnT)[i];
    float4 o;
    o.x = v0.x + v1.x + v2.x + v3.x + bv.x + rv.x;
    o.y = v0.y + v1.y + v2.y + v3.y + bv.y + rv.y;
    o.z = v0.z + v1.z + v2.z + v3.z + bv.z + rv.z;
    o.w = v0.w + v1.w + v2.w + v3.w + bv.w + rv.w;
    ((float4*)Xn)[i] = o;
    ushort4 hv, lv;
    splitf(o.x, hv.x, lv.x);
    splitf(o.y, hv.y, lv.y);
    splitf(o.z, hv.z, lv.z);
    splitf(o.w, hv.w, lv.w);
    ((ushort4*)Xhi)[i] = hv;
    ((ushort4*)Xlo)[i] = lv;
}

__global__ __launch_bounds__(256) void transpose_k(
    const float* __restrict__ src, float* __restrict__ dst, int R, int C)
{
    __shared__ float t[32][33];
    int tx = threadIdx.x & 31, ty = threadIdx.x >> 5;
    int c0 = blockIdx.x * 32, r0 = blockIdx.y * 32;
#pragma unroll
    for (int k = 0; k < 4; k++)
        t[ty + 8 * k][tx] = src[(long)(r0 + ty + 8 * k) * C + c0 + tx];
    __syncthreads();
#pragma unroll
    for (int k = 0; k < 4; k++)
        dst[(long)(c0 + ty + 8 * k) * R + r0 + tx] = t[tx][ty + 8 * k];
}

// ---------------------------------------------------------------------------
// Workspace layout identical to R8 (~87 MB < proven 94.4 MB).
// ---------------------------------------------------------------------------
extern "C" void kernel_launch(void* const* d_in, const int* in_sizes, int n_in,
                              void* d_out, int out_size, void* d_ws, size_t ws_size,
                              hipStream_t stream)
{
    const float* X0 = (const float*)d_in[0];
    const float* Kw = (const float*)d_in[1];
    const float* Vw = (const float*)d_in[2];
    const float* W1 = (const float*)d_in[3];
    const float* b1 = (const float*)d_in[4];
    const float* W2 = (const float*)d_in[5];
    const float* b2 = (const float*)d_in[6];
    float* out = (float*)d_out;

    float* R0    = (float*)d_ws;
    float* Yt    = R0;                       // 4,194,304  [H,NN,DD] fp32
    u16*   ff1hi = (u16*)(R0 + 4194304);
    u16*   ff1lo = (u16*)(R0 + 6291456);
    float* Cpart = R0 + 8388608;             // 4,194,304
    float* attnT = R0 + 12582912;            // 1,048,576

    float* ext = R0 + 13631488;
    u16* KXThi = (u16*)ext;                  // 262,144 words
    u16* KXTlo = (u16*)(ext + 262144);
    float* XbufA = ext + 524288;             // 1,048,576
    float* XbufB = ext + 1572864;            // 1,048,576
    u16* Xhi  = (u16*)(ext + 2621440);       // 524,288 words
    u16* Xlo  = (u16*)(ext + 3145728);
    u16* athi = (u16*)(ext + 3670016);
    u16* atlo = (u16*)(ext + 4194304);
    u16* Khi  = (u16*)(ext + 4718592);       // 65,536 words
    u16* Klo  = (u16*)(ext + 4784128);
    u16* Vhi  = (u16*)(ext + 4849664);       // 524,288 words
    u16* Vlo  = (u16*)(ext + 5373952);
    u16* W1hi = (u16*)(ext + 5898240);
    u16* W1lo = (u16*)(ext + 6422528);
    u16* W2hi = (u16*)(ext + 6946816);
    u16* W2lo = (u16*)(ext + 7471104);
    float* wrecip = ext + 7995392;           // 8,192
    unsigned int* entries = (unsigned int*)(ext + 8003584);  // 131,072
    unsigned int* csr     = (unsigned int*)(ext + 8134656);  // 131,072
    int* colOff   = (int*)(ext + 8265728);   // 2,112
    int* counters = (int*)(ext + 8267840);   // 64
    unsigned* rowmaxU = (unsigned*)(ext + 8267904);  // 8,192
    int* rowcnt   = (int*)(ext + 8276096);   // 8,192 (adjacent to rowmaxU)

    zero_k<<<1, 64, 0, stream>>>(counters);

    // XT0 = X0^T [N, D]; split to bf16 hi/lo
    transpose_k<<<dim3(NN / 32, DD / 32), 256, 0, stream>>>(X0, XbufA, DD, NN);
    split_k<<<dim3(1024), 256, 0, stream>>>(XbufA, Xhi, Xlo);

    float* Xc = XbufA;
    for (int li = 0; li < LL; li++) {
        float* Xn = (li & 1) ? XbufA : XbufB;

        // 0) split this layer's weights to bf16 hi/lo
        splitw_k<<<dim3(3200), 256, 0, stream>>>(
            Kw + (long)li * 131072, Vw + (long)li * 1048576,
            W1 + (long)li * 1048576, W2 + (long)li * 1048576,
            Khi, Klo, Vhi, Vlo, W1hi, W1lo, W2hi, W2lo);

        // 1) KXT = XT @ Kw^T  [2048, 256], K=512 -> hi/lo. MI=1: 128 blocks.
        mgemm_k<1, 0, 0, 0, 1><<<dim3(2, 64, 1), 256, 0, stream>>>(
            Xhi, Xlo, Khi, Klo, nullptr, KXThi, KXTlo, nullptr,
            NN, HH * QQ, DD, DD, DD, HH * QQ, 0, 0, 0);

        // 2) fused mask path: no S materialization
        initrow_k<<<dim3(64), 256, 0, stream>>>(rowmaxU);   // zeroes rowcnt too
        smax_k<<<dim3(16, 16, HH), 256, 0, stream>>>(KXThi, KXTlo, rowmaxU);
        sextract_k<<<dim3(16, 16, HH), 256, 0, stream>>>(
            KXThi, KXTlo, rowmaxU, rowcnt, entries, counters + li);
        wrecip_k<<<dim3(32), 256, 0, stream>>>(rowmaxU, rowcnt, wrecip);
        buildcsr_k<<<dim3(1), 256, 0, stream>>>(entries, counters + li, csr, colOff);

        // 4) Yt_h = XT @ V_h^T  [NN, DD] fp32, batch H. MI=2: 512 blocks.
        mgemm_k<2, 0, 0, 1, 0><<<dim3(4, 32, HH), 256, 0, stream>>>(
            Xhi, Xlo, Vhi, Vlo, Yt, nullptr, nullptr, nullptr,
            NN, DD, DD, DD, DD, DD, 0, (long)DD * DD, (long)NN * DD);

        // 5) attnT = XT + sparse combine; then split for FF1 input
        initattn_k<<<dim3(NN * DD / 4 / 256), 256, 0, stream>>>(Xc, attnT);
        apply_k<<<dim3(APPLY_BLOCKS), 256, 0, stream>>>(csr, colOff, wrecip, Yt, attnT);
        split_k<<<dim3(1024), 256, 0, stream>>>(attnT, athi, atlo);

        // 6) ff1 = relu(attnT @ W1^T + b1)  [NN, DFF] -> hi/lo. MI=2: 512 blk.
        mgemm_k<2, 1, 1, 0, 1><<<dim3(16, 32, 1), 256, 0, stream>>>(
            athi, atlo, W1hi, W1lo, nullptr, ff1hi, ff1lo,
            b1 + (long)li * DFFC,
            NN, DFFC, DD, DD, DD, DFFC, 0, 0, 0);

        // 7) FF2 split-K=4, MI=2: 512 blocks.
        mgemm_k<2, 0, 0, 1, 0><<<dim3(4, 32, 4), 256, 0, stream>>>(
            ff1hi, ff1lo, W2hi, W2lo, Cpart, nullptr, nullptr, nullptr,
            NN, DD, 512, DFFC, DFFC, DD, 512, 512, (long)NN * DD);
        ff2red_k<<<dim3(1024), 256, 0, stream>>>(
            Cpart, b2 + (long)li * DD, attnT, Xn, Xhi, Xlo);

        Xc = Xn;
    }

    // out = XT_final^T  [D, N]
    transpose_k<<<dim3(DD / 32, NN / 32), 256, 0, stream>>>(Xc, out, NN, DD);
}

// Round 10
// 1970.348 us; speedup vs baseline: 1.1995x; 1.1995x over previous
//
#include <hip/hip_runtime.h>

// Problem constants
#define LL   8
#define HH   4
#define QQ   64
#define DD   512
#define NN   2048
#define DFFC 2048
#define ENTRY_CAP (1 << 17)
#define CHUNK 8
#define APPLY_BLOCKS 2048
#define LCAP 2048   // per-block LDS entry staging capacity

typedef short     bf16x8 __attribute__((ext_vector_type(8)));  // 8 bf16 = 4 VGPR
typedef float     f32x4  __attribute__((ext_vector_type(4)));  // MFMA C/D frag
typedef unsigned short u16;

// fp32 -> (hi, lo) bf16 split, RNE. x ~= hi + lo with ~16-bit mantissa coverage.
__device__ inline void splitf(float v, u16& h, u16& l)
{
    unsigned u  = __float_as_uint(v);
    unsigned uh = u + (0x7FFFu + ((u >> 16) & 1u));
    h = (u16)(uh >> 16);
    float fh = __uint_as_float(((unsigned)h) << 16);
    float r  = v - fh;
    unsigned ur = __float_as_uint(r);
    unsigned ul = ur + (0x7FFFu + ((ur >> 16) & 1u));
    l = (u16)(ul >> 16);
}

// Monotone fp32 <-> uint mapping for atomicMax on floats (no NaNs in data).
__device__ inline unsigned mapf(float f)
{
    unsigned u = __float_as_uint(f);
    return (u >> 31) ? ~u : (u | 0x80000000u);
}
__device__ inline float unmapf(unsigned u)
{
    return (u >> 31) ? __uint_as_float(u ^ 0x80000000u) : __uint_as_float(~u);
}

// ---------------------------------------------------------------------------
// Split-bf16 MFMA GEMM (NT): C[M,N] = A[M,K] @ B[N,K]^T as hi*hi+hi*lo+lo*hi
// (fp32 accumulate). Block 256 thr = 4 waves (2x2). Col tile 128; row tile
// MI*32. 2-stage REGISTER PIPELINE: fragments for k+32 are loaded while
// MFMAing k (grid is 1 block/CU -> ILP is the only latency hiding; at
// 1 wave/SIMD up to ~512 VGPR is occupancy-free). K must be multiple of 64.
// ---------------------------------------------------------------------------
template <int MI, int BIAS, int RELU, int WF32, int WSPLIT>
__global__ __launch_bounds__(256) void mgemm_k(
    const u16* __restrict__ Ahi, const u16* __restrict__ Alo,
    const u16* __restrict__ Bhi, const u16* __restrict__ Blo,
    float* __restrict__ C, u16* __restrict__ Chi, u16* __restrict__ Clo,
    const float* __restrict__ bias,
    int M, int N, int K, int lda, int ldb, int ldc,
    long sAoff, long sBoff, long sCoff)
{
    const int bz = blockIdx.z;
    Ahi += bz * sAoff;  Alo += bz * sAoff;
    Bhi += bz * sBoff;  Blo += bz * sBoff;
    const long cOff = (long)bz * sCoff;

    const int tid  = threadIdx.x;
    const int wave = tid >> 6, lane = tid & 63;
    const int quad = lane >> 4, l15 = lane & 15;
    const int wy = wave >> 1, wx = wave & 1;
    const int mBase = blockIdx.y * (MI * 32) + wy * (MI * 16);
    const int nBase = blockIdx.x * 128 + wx * 64;
    const int quad8 = quad * 8;

    long aRow[MI], bRow[4];
#pragma unroll
    for (int i = 0; i < MI; i++) aRow[i] = (long)(mBase + i * 16 + l15) * lda + quad8;
#pragma unroll
    for (int j = 0; j < 4; j++)  bRow[j] = (long)(nBase + j * 16 + l15) * ldb + quad8;

    f32x4 acc[MI][4];
#pragma unroll
    for (int i = 0; i < MI; i++)
#pragma unroll
        for (int j = 0; j < 4; j++)
            acc[i][j] = (f32x4){0.f, 0.f, 0.f, 0.f};

    bf16x8 ah0[MI], al0[MI], bh0[4], bl0[4];
    bf16x8 ah1[MI], al1[MI], bh1[4], bl1[4];

#define LOADSET(dst_ah, dst_al, dst_bh, dst_bl, koff)                        \
    {                                                                        \
        _Pragma("unroll")                                                    \
        for (int i = 0; i < MI; i++) {                                       \
            dst_ah[i] = *(const bf16x8*)(Ahi + aRow[i] + (koff));            \
            dst_al[i] = *(const bf16x8*)(Alo + aRow[i] + (koff));            \
        }                                                                    \
        _Pragma("unroll")                                                    \
        for (int j = 0; j < 4; j++) {                                        \
            dst_bh[j] = *(const bf16x8*)(Bhi + bRow[j] + (koff));            \
            dst_bl[j] = *(const bf16x8*)(Blo + bRow[j] + (koff));            \
        }                                                                    \
    }

#define MFMASET(s_ah, s_al, s_bh, s_bl)                                      \
    {                                                                        \
        _Pragma("unroll")                                                    \
        for (int i = 0; i < MI; i++)                                         \
            _Pragma("unroll")                                                \
            for (int j = 0; j < 4; j++) {                                    \
                acc[i][j] = __builtin_amdgcn_mfma_f32_16x16x32_bf16(         \
                    s_ah[i], s_bh[j], acc[i][j], 0, 0, 0);                   \
                acc[i][j] = __builtin_amdgcn_mfma_f32_16x16x32_bf16(         \
                    s_ah[i], s_bl[j], acc[i][j], 0, 0, 0);                   \
                acc[i][j] = __builtin_amdgcn_mfma_f32_16x16x32_bf16(         \
                    s_al[i], s_bh[j], acc[i][j], 0, 0, 0);                   \
            }                                                                \
    }

    LOADSET(ah0, al0, bh0, bl0, 0)
    for (int k0 = 0; k0 < K; k0 += 64) {
        if (k0 + 32 < K) LOADSET(ah1, al1, bh1, bl1, k0 + 32)
        MFMASET(ah0, al0, bh0, bl0)
        if (k0 + 64 < K) LOADSET(ah0, al0, bh0, bl0, k0 + 64)
        if (k0 + 32 < K) MFMASET(ah1, al1, bh1, bl1)
    }

#pragma unroll
    for (int i = 0; i < MI; i++) {
#pragma unroll
        for (int j = 0; j < 4; j++) {
            const int n = nBase + j * 16 + l15;
            const float bv = BIAS ? bias[n] : 0.0f;
#pragma unroll
            for (int r = 0; r < 4; r++) {
                const int m = mBase + i * 16 + quad * 4 + r;
                float v = acc[i][j][r] + bv;
                if (RELU) v = fmaxf(v, 0.0f);
                const long o = cOff + (long)m * ldc + n;
                if (WF32) C[o] = v;
                if (WSPLIT) {
                    u16 h, l;
                    splitf(v, h, l);
                    Chi[o] = h;
                    Clo[o] = l;
                }
            }
        }
    }
}

// ---------------------------------------------------------------------------
// Fused mask path, pass A: per-head Gram tile S = G G^T in regs; row-max
// reduce -> global atomicMax. K=64: ALL fragments (both k-steps) preloaded
// before any MFMA (full ILP).
// ---------------------------------------------------------------------------
__global__ __launch_bounds__(256) void smax_k(
    const u16* __restrict__ Ghi, const u16* __restrict__ Glo,
    unsigned* __restrict__ rowmaxU)
{
    const int h = blockIdx.z;
    const u16* Ah = Ghi + h * QQ;
    const u16* Al = Glo + h * QQ;
    const int lda = HH * QQ;

    const int tid  = threadIdx.x;
    const int wave = tid >> 6, lane = tid & 63;
    const int quad = lane >> 4, l15 = lane & 15;
    const int wy = wave >> 1, wx = wave & 1;
    const int rB = blockIdx.y * 128 + wy * 64;
    const int cB = blockIdx.x * 128 + wx * 64;

    bf16x8 ah[2][4], al[2][4], bh[2][4], bl[2][4];
#pragma unroll
    for (int s = 0; s < 2; s++) {
        const int kk = s * 32 + quad * 8;
#pragma unroll
        for (int i = 0; i < 4; i++) {
            long ar = (long)(rB + i * 16 + l15) * lda + kk;
            ah[s][i] = *(const bf16x8*)(Ah + ar);
            al[s][i] = *(const bf16x8*)(Al + ar);
            long br = (long)(cB + i * 16 + l15) * lda + kk;
            bh[s][i] = *(const bf16x8*)(Ah + br);
            bl[s][i] = *(const bf16x8*)(Al + br);
        }
    }

    f32x4 acc[4][4];
#pragma unroll
    for (int i = 0; i < 4; i++)
#pragma unroll
        for (int j = 0; j < 4; j++)
            acc[i][j] = (f32x4){0.f, 0.f, 0.f, 0.f};

#pragma unroll
    for (int s = 0; s < 2; s++)
#pragma unroll
        for (int i = 0; i < 4; i++)
#pragma unroll
            for (int j = 0; j < 4; j++) {
                acc[i][j] = __builtin_amdgcn_mfma_f32_16x16x32_bf16(ah[s][i], bh[s][j], acc[i][j], 0, 0, 0);
                acc[i][j] = __builtin_amdgcn_mfma_f32_16x16x32_bf16(ah[s][i], bl[s][j], acc[i][j], 0, 0, 0);
                acc[i][j] = __builtin_amdgcn_mfma_f32_16x16x32_bf16(al[s][i], bh[s][j], acc[i][j], 0, 0, 0);
            }

#pragma unroll
    for (int i = 0; i < 4; i++)
#pragma unroll
        for (int r = 0; r < 4; r++) {
            float mx = acc[i][0][r];
#pragma unroll
            for (int j = 1; j < 4; j++) mx = fmaxf(mx, acc[i][j][r]);
#pragma unroll
            for (int off = 1; off < 16; off <<= 1)
                mx = fmaxf(mx, __shfl_xor(mx, off, 64));
            if (l15 == 0)
                atomicMax(&rowmaxU[h * NN + rB + i * 16 + quad * 4 + r], mapf(mx));
        }
}

// ---------------------------------------------------------------------------
// Fused mask path, pass B: recompute IDENTICAL S tile (same per-(i,j) MFMA
// order as smax -> same bits), threshold, count, emit entries via LDS
// staging + one global atomicAdd per block. Full fragment preload (K=64).
// ---------------------------------------------------------------------------
__global__ __launch_bounds__(256) void sextract_k(
    const u16* __restrict__ Ghi, const u16* __restrict__ Glo,
    const unsigned* __restrict__ rowmaxU, int* __restrict__ rowcnt,
    unsigned int* __restrict__ entries, int* __restrict__ counter)
{
    const int h = blockIdx.z;
    const u16* Ah = Ghi + h * QQ;
    const u16* Al = Glo + h * QQ;
    const int lda = HH * QQ;

    const int tid  = threadIdx.x;
    const int wave = tid >> 6, lane = tid & 63;
    const int quad = lane >> 4, l15 = lane & 15;
    const int wy = wave >> 1, wx = wave & 1;
    const int rB = blockIdx.y * 128 + wy * 64;
    const int cB = blockIdx.x * 128 + wx * 64;

    __shared__ float thrS[128];
    __shared__ unsigned lbuf[LCAP];
    __shared__ int lcnt, gbase;
    if (tid == 0) lcnt = 0;
    if (tid < 128) {
        float mx = unmapf(rowmaxU[h * NN + blockIdx.y * 128 + tid]);
        thrS[tid] = (fabsf(mx) > 0.5f) ? mx - 0.5f : 3.402823466e38f;
    }
    __syncthreads();

    bf16x8 ah[2][4], al[2][4], bh[2][4], bl[2][4];
#pragma unroll
    for (int s = 0; s < 2; s++) {
        const int kk = s * 32 + quad * 8;
#pragma unroll
        for (int i = 0; i < 4; i++) {
            long ar = (long)(rB + i * 16 + l15) * lda + kk;
            ah[s][i] = *(const bf16x8*)(Ah + ar);
            al[s][i] = *(const bf16x8*)(Al + ar);
            long br = (long)(cB + i * 16 + l15) * lda + kk;
            bh[s][i] = *(const bf16x8*)(Ah + br);
            bl[s][i] = *(const bf16x8*)(Al + br);
        }
    }

    f32x4 acc[4][4];
#pragma unroll
    for (int i = 0; i < 4; i++)
#pragma unroll
        for (int j = 0; j < 4; j++)
            acc[i][j] = (f32x4){0.f, 0.f, 0.f, 0.f};

#pragma unroll
    for (int s = 0; s < 2; s++)
#pragma unroll
        for (int i = 0; i < 4; i++)
#pragma unroll
            for (int j = 0; j < 4; j++) {
                acc[i][j] = __builtin_amdgcn_mfma_f32_16x16x32_bf16(ah[s][i], bh[s][j], acc[i][j], 0, 0, 0);
                acc[i][j] = __builtin_amdgcn_mfma_f32_16x16x32_bf16(ah[s][i], bl[s][j], acc[i][j], 0, 0, 0);
                acc[i][j] = __builtin_amdgcn_mfma_f32_16x16x32_bf16(al[s][i], bh[s][j], acc[i][j], 0, 0, 0);
            }

#pragma unroll
    for (int i = 0; i < 4; i++) {
#pragma unroll
        for (int r = 0; r < 4; r++) {
            const int lr  = wy * 64 + i * 16 + quad * 4 + r;
            const int row = h * NN + rB + i * 16 + quad * 4 + r;
            const float thr = thrS[lr];

            int c = 0;
#pragma unroll
            for (int j = 0; j < 4; j++) c += (acc[i][j][r] >= thr) ? 1 : 0;
            int cs = c;
#pragma unroll
            for (int off = 1; off < 16; off <<= 1) cs += __shfl_xor(cs, off, 64);
            if (l15 == 0 && cs > 0) atomicAdd(&rowcnt[row], cs);

#pragma unroll
            for (int j = 0; j < 4; j++) {
                if (acc[i][j][r] >= thr) {
                    unsigned ent = ((unsigned)row << 11) |
                                   (unsigned)(cB + j * 16 + l15);
                    int s2 = atomicAdd(&lcnt, 1);
                    if (s2 < LCAP) {
                        lbuf[s2] = ent;
                    } else {
                        unsigned p = (unsigned)atomicAdd(counter, 1);
                        if (p < ENTRY_CAP) entries[p] = ent;
                    }
                }
            }
        }
    }

    __syncthreads();
    int n = lcnt;
    if (n > LCAP) n = LCAP;
    if (n > 0) {
        if (tid == 0) gbase = atomicAdd(counter, n);
        __syncthreads();
        for (int i2 = tid; i2 < n; i2 += 256) {
            unsigned p = (unsigned)(gbase + i2);
            if (p < ENTRY_CAP) entries[p] = lbuf[i2];
        }
    }
}

// ---------------------------------------------------------------------------
// initrow / wrecip / split / splitw / zero / buildcsr / initattn / apply /
// ff2red / transpose  (unchanged from R8/R9-passing code)
// ---------------------------------------------------------------------------
__global__ __launch_bounds__(256) void initrow_k(unsigned* __restrict__ p)
{
    p[blockIdx.x * 256 + threadIdx.x] = 0u;
}

__global__ __launch_bounds__(256) void wrecip_k(
    const unsigned* __restrict__ rowmaxU, const int* __restrict__ rowcnt,
    float* __restrict__ wrecip)
{
    int i = blockIdx.x * 256 + threadIdx.x;
    float mx = unmapf(rowmaxU[i]);
    wrecip[i] = (fabsf(mx) > 0.5f) ? 1.0f / fmaxf((float)rowcnt[i], 1.0f) : 0.0f;
}

__global__ __launch_bounds__(256) void split_k(
    const float* __restrict__ src, u16* __restrict__ hi, u16* __restrict__ lo)
{
    int i = blockIdx.x * 256 + threadIdx.x;
    float4 v = ((const float4*)src)[i];
    ushort4 hv, lv;
    splitf(v.x, hv.x, lv.x);
    splitf(v.y, hv.y, lv.y);
    splitf(v.z, hv.z, lv.z);
    splitf(v.w, hv.w, lv.w);
    ((ushort4*)hi)[i] = hv;
    ((ushort4*)lo)[i] = lv;
}

__global__ __launch_bounds__(256) void splitw_k(
    const float* __restrict__ K_, const float* __restrict__ V_,
    const float* __restrict__ W1_, const float* __restrict__ W2_,
    u16* __restrict__ Khi, u16* __restrict__ Klo,
    u16* __restrict__ Vhi, u16* __restrict__ Vlo,
    u16* __restrict__ W1hi, u16* __restrict__ W1lo,
    u16* __restrict__ W2hi, u16* __restrict__ W2lo)
{
    int i = blockIdx.x * 256 + threadIdx.x;
    const float* s;
    u16 *h, *l;
    int off;
    if (i < 32768)       { s = K_;  h = Khi;  l = Klo;  off = i; }
    else if (i < 294912) { s = V_;  h = Vhi;  l = Vlo;  off = i - 32768; }
    else if (i < 557056) { s = W1_; h = W1hi; l = W1lo; off = i - 294912; }
    else                 { s = W2_; h = W2hi; l = W2lo; off = i - 557056; }
    float4 v = ((const float4*)s)[off];
    ushort4 hv, lv;
    splitf(v.x, hv.x, lv.x);
    splitf(v.y, hv.y, lv.y);
    splitf(v.z, hv.z, lv.z);
    splitf(v.w, hv.w, lv.w);
    ((ushort4*)h)[off] = hv;
    ((ushort4*)l)[off] = lv;
}

__global__ void zero_k(int* __restrict__ counters)
{
    if (threadIdx.x < LL) counters[threadIdx.x] = 0;
}

__global__ __launch_bounds__(256) void buildcsr_k(
    const unsigned int* __restrict__ entries, const int* __restrict__ counter,
    unsigned int* __restrict__ csr, int* __restrict__ colOff)
{
    __shared__ int hist[NN];
    __shared__ int part[256];
    const int t = threadIdx.x;
    int cnt = *counter;
    if (cnt > ENTRY_CAP) cnt = ENTRY_CAP;

    for (int i = t; i < NN; i += 256) hist[i] = 0;
    __syncthreads();
    for (int i = t; i < cnt; i += 256)
        atomicAdd(&hist[entries[i] & 2047], 1);
    __syncthreads();

    int e[8];
    int s = 0;
#pragma unroll
    for (int i = 0; i < 8; i++) { e[i] = s; s += hist[t * 8 + i]; }
    part[t] = s;
    __syncthreads();
    for (int off = 1; off < 256; off <<= 1) {
        int x = (t >= off) ? part[t - off] : 0;
        __syncthreads();
        part[t] += x;
        __syncthreads();
    }
    int base = (t > 0) ? part[t - 1] : 0;
    int my[8];
#pragma unroll
    for (int i = 0; i < 8; i++) my[i] = base + e[i];
#pragma unroll
    for (int i = 0; i < 8; i++) colOff[t * 8 + i] = my[i];
    if (t == 255) colOff[NN] = part[255];
    __syncthreads();
#pragma unroll
    for (int i = 0; i < 8; i++) hist[t * 8 + i] = my[i];
    __syncthreads();

    for (int i = t; i < cnt; i += 256) {
        unsigned v = entries[i];
        int slot = atomicAdd(&hist[v & 2047], 1);
        csr[slot] = v;
    }
}

__global__ __launch_bounds__(256) void initattn_k(
    const float* __restrict__ X, float* __restrict__ attnT)
{
    long i = (long)blockIdx.x * 256 + threadIdx.x;
    ((float4*)attnT)[i] = ((const float4*)X)[i];
}

__global__ __launch_bounds__(256) void apply_k(
    const unsigned int* __restrict__ csr, const int* __restrict__ colOff,
    const float* __restrict__ wrecip, const float* __restrict__ Yt,
    float* __restrict__ attnT)
{
    const int total = colOff[NN];
    const int tid = threadIdx.x;

    for (int base = blockIdx.x * CHUNK; base < total;
         base += gridDim.x * CHUNK) {
        int end = base + CHUNK;
        if (end > total) end = total;

        float a0 = 0.0f, a1 = 0.0f;
        int curM = -1;
        for (int e = base; e < end; e++) {
            unsigned v = csr[e];
            int m = v & 2047;
            int row = (int)(v >> 11);
            if (m != curM) {
                if (curM >= 0) {
                    atomicAdd(&attnT[(long)curM * DD + tid], a0);
                    atomicAdd(&attnT[(long)curM * DD + tid + 256], a1);
                }
                curM = m;
                a0 = a1 = 0.0f;
            }
            float w = wrecip[row];
            const float* y = Yt + (long)row * DD;
            a0 += w * y[tid];
            a1 += w * y[tid + 256];
        }
        if (curM >= 0) {
            atomicAdd(&attnT[(long)curM * DD + tid], a0);
            atomicAdd(&attnT[(long)curM * DD + tid + 256], a1);
        }
    }
}

__global__ __launch_bounds__(256) void ff2red_k(
    const float* __restrict__ Cpart, const float* __restrict__ b2,
    const float* __restrict__ attnT, float* __restrict__ Xn,
    u16* __restrict__ Xhi, u16* __restrict__ Xlo)
{
    int i = blockIdx.x * 256 + threadIdx.x;
    float4 v0 = ((const float4*)(Cpart))[i];
    float4 v1 = ((const float4*)(Cpart + 1048576))[i];
    float4 v2 = ((const float4*)(Cpart + 2097152))[i];
    float4 v3 = ((const float4*)(Cpart + 3145728))[i];
    float4 bv = ((const float4*)b2)[i & 127];
    float4 rv = ((const float4*)attnT)[i];
    float4 o;
    o.x = v0.x + v1.x + v2.x + v3.x + bv.x + rv.x;
    o.y = v0.y + v1.y + v2.y + v3.y + bv.y + rv.y;
    o.z = v0.z + v1.z + v2.z + v3.z + bv.z + rv.z;
    o.w = v0.w + v1.w + v2.w + v3.w + bv.w + rv.w;
    ((float4*)Xn)[i] = o;
    ushort4 hv, lv;
    splitf(o.x, hv.x, lv.x);
    splitf(o.y, hv.y, lv.y);
    splitf(o.z, hv.z, lv.z);
    splitf(o.w, hv.w, lv.w);
    ((ushort4*)Xhi)[i] = hv;
    ((ushort4*)Xlo)[i] = lv;
}

__global__ __launch_bounds__(256) void transpose_k(
    const float* __restrict__ src, float* __restrict__ dst, int R, int C)
{
    __shared__ float t[32][33];
    int tx = threadIdx.x & 31, ty = threadIdx.x >> 5;
    int c0 = blockIdx.x * 32, r0 = blockIdx.y * 32;
#pragma unroll
    for (int k = 0; k < 4; k++)
        t[ty + 8 * k][tx] = src[(long)(r0 + ty + 8 * k) * C + c0 + tx];
    __syncthreads();
#pragma unroll
    for (int k = 0; k < 4; k++)
        dst[(long)(c0 + ty + 8 * k) * R + r0 + tx] = t[tx][ty + 8 * k];
}

// ---------------------------------------------------------------------------
// Workspace layout identical to R8/R9 (~87 MB < proven 94.4 MB).
// ---------------------------------------------------------------------------
extern "C" void kernel_launch(void* const* d_in, const int* in_sizes, int n_in,
                              void* d_out, int out_size, void* d_ws, size_t ws_size,
                              hipStream_t stream)
{
    const float* X0 = (const float*)d_in[0];
    const float* Kw = (const float*)d_in[1];
    const float* Vw = (const float*)d_in[2];
    const float* W1 = (const float*)d_in[3];
    const float* b1 = (const float*)d_in[4];
    const float* W2 = (const float*)d_in[5];
    const float* b2 = (const float*)d_in[6];
    float* out = (float*)d_out;

    float* R0    = (float*)d_ws;
    float* Yt    = R0;                       // 4,194,304  [H,NN,DD] fp32
    u16*   ff1hi = (u16*)(R0 + 4194304);
    u16*   ff1lo = (u16*)(R0 + 6291456);
    float* Cpart = R0 + 8388608;             // 4,194,304
    float* attnT = R0 + 12582912;            // 1,048,576

    float* ext = R0 + 13631488;
    u16* KXThi = (u16*)ext;                  // 262,144 words
    u16* KXTlo = (u16*)(ext + 262144);
    float* XbufA = ext + 524288;             // 1,048,576
    float* XbufB = ext + 1572864;            // 1,048,576
    u16* Xhi  = (u16*)(ext + 2621440);       // 524,288 words
    u16* Xlo  = (u16*)(ext + 3145728);
    u16* athi = (u16*)(ext + 3670016);
    u16* atlo = (u16*)(ext + 4194304);
    u16* Khi  = (u16*)(ext + 4718592);       // 65,536 words
    u16* Klo  = (u16*)(ext + 4784128);
    u16* Vhi  = (u16*)(ext + 4849664);       // 524,288 words
    u16* Vlo  = (u16*)(ext + 5373952);
    u16* W1hi = (u16*)(ext + 5898240);
    u16* W1lo = (u16*)(ext + 6422528);
    u16* W2hi = (u16*)(ext + 6946816);
    u16* W2lo = (u16*)(ext + 7471104);
    float* wrecip = ext + 7995392;           // 8,192
    unsigned int* entries = (unsigned int*)(ext + 8003584);  // 131,072
    unsigned int* csr     = (unsigned int*)(ext + 8134656);  // 131,072
    int* colOff   = (int*)(ext + 8265728);   // 2,112
    int* counters = (int*)(ext + 8267840);   // 64
    unsigned* rowmaxU = (unsigned*)(ext + 8267904);  // 8,192
    int* rowcnt   = (int*)(ext + 8276096);   // 8,192 (adjacent to rowmaxU)

    zero_k<<<1, 64, 0, stream>>>(counters);

    // XT0 = X0^T [N, D]; split to bf16 hi/lo
    transpose_k<<<dim3(NN / 32, DD / 32), 256, 0, stream>>>(X0, XbufA, DD, NN);
    split_k<<<dim3(1024), 256, 0, stream>>>(XbufA, Xhi, Xlo);

    float* Xc = XbufA;
    for (int li = 0; li < LL; li++) {
        float* Xn = (li & 1) ? XbufA : XbufB;

        // 0) split this layer's weights to bf16 hi/lo
        splitw_k<<<dim3(3200), 256, 0, stream>>>(
            Kw + (long)li * 131072, Vw + (long)li * 1048576,
            W1 + (long)li * 1048576, W2 + (long)li * 1048576,
            Khi, Klo, Vhi, Vlo, W1hi, W1lo, W2hi, W2lo);

        // 1) KXT = XT @ Kw^T  [2048, 256], K=512 -> hi/lo. MI=1: 128 blocks.
        mgemm_k<1, 0, 0, 0, 1><<<dim3(2, 64, 1), 256, 0, stream>>>(
            Xhi, Xlo, Khi, Klo, nullptr, KXThi, KXTlo, nullptr,
            NN, HH * QQ, DD, DD, DD, HH * QQ, 0, 0, 0);

        // 2) fused mask path: no S materialization
        initrow_k<<<dim3(64), 256, 0, stream>>>(rowmaxU);   // zeroes rowcnt too
        smax_k<<<dim3(16, 16, HH), 256, 0, stream>>>(KXThi, KXTlo, rowmaxU);
        sextract_k<<<dim3(16, 16, HH), 256, 0, stream>>>(
            KXThi, KXTlo, rowmaxU, rowcnt, entries, counters + li);
        wrecip_k<<<dim3(32), 256, 0, stream>>>(rowmaxU, rowcnt, wrecip);
        buildcsr_k<<<dim3(1), 256, 0, stream>>>(entries, counters + li, csr, colOff);

        // 4) Yt_h = XT @ V_h^T  [NN, DD] fp32, batch H. MI=4: 256 blocks.
        mgemm_k<4, 0, 0, 1, 0><<<dim3(4, 16, HH), 256, 0, stream>>>(
            Xhi, Xlo, Vhi, Vlo, Yt, nullptr, nullptr, nullptr,
            NN, DD, DD, DD, DD, DD, 0, (long)DD * DD, (long)NN * DD);

        // 5) attnT = XT + sparse combine; then split for FF1 input
        initattn_k<<<dim3(NN * DD / 4 / 256), 256, 0, stream>>>(Xc, attnT);
        apply_k<<<dim3(APPLY_BLOCKS), 256, 0, stream>>>(csr, colOff, wrecip, Yt, attnT);
        split_k<<<dim3(1024), 256, 0, stream>>>(attnT, athi, atlo);

        // 6) ff1 = relu(attnT @ W1^T + b1)  [NN, DFF] -> hi/lo. MI=4: 256 blk.
        mgemm_k<4, 1, 1, 0, 1><<<dim3(16, 16, 1), 256, 0, stream>>>(
            athi, atlo, W1hi, W1lo, nullptr, ff1hi, ff1lo,
            b1 + (long)li * DFFC,
            NN, DFFC, DD, DD, DD, DFFC, 0, 0, 0);

        // 7) FF2 split-K=4, MI=4: 256 blocks.
        mgemm_k<4, 0, 0, 1, 0><<<dim3(4, 16, 4), 256, 0, stream>>>(
            ff1hi, ff1lo, W2hi, W2lo, Cpart, nullptr, nullptr, nullptr,
            NN, DD, 512, DFFC, DFFC, DD, 512, 512, (long)NN * DD);
        ff2red_k<<<dim3(1024), 256, 0, stream>>>(
            Cpart, b2 + (long)li * DD, attnT, Xn, Xhi, Xlo);

        Xc = Xn;
    }

    // out = XT_final^T  [D, N]
    transpose_k<<<dim3(DD / 32, NN / 32), 256, 0, stream>>>(Xc, out, NN, DD);
}